// Round 1
// baseline (4661.420 us; speedup 1.0000x reference)
//
#include <hip/hip_runtime.h>
#include <hip/hip_bf16.h>

typedef __attribute__((ext_vector_type(8))) short short8;
typedef __attribute__((ext_vector_type(4))) float f32x4;

#define NROWS 38400      // B*L = 8*4800
#define LSEQ 4800
#define BATCH 8
#define NHEAD 8
#define HDIM 32

// ---------------------------------------------------------------------------
// Tiled transpose + fp32->bf16 convert: dst[c][r] = src[r][c]. R,C multiples of 32.
// ---------------------------------------------------------------------------
__global__ __launch_bounds__(256) void transpose_bf16(
    const float* __restrict__ src, __hip_bfloat16* __restrict__ dst, int R, int C) {
  __shared__ float tile[32][33];
  int bx = blockIdx.x, by = blockIdx.y;
  int tx = threadIdx.x & 31, ty = threadIdx.x >> 5;  // ty in 0..7
  for (int rr = ty; rr < 32; rr += 8) {
    tile[rr][tx] = src[(long)(by * 32 + rr) * C + bx * 32 + tx];
  }
  __syncthreads();
  for (int rr = ty; rr < 32; rr += 8) {
    dst[(long)(bx * 32 + rr) * R + by * 32 + tx] = __float2bfloat16(tile[tx][rr]);
  }
}

// ---------------------------------------------------------------------------
// Init: copy fp32 descriptors into d_out (residual stream) and bf16 mirrors.
// ---------------------------------------------------------------------------
__global__ __launch_bounds__(256) void init_x(
    const float* __restrict__ d0, const float* __restrict__ d1,
    float* __restrict__ outF, __hip_bfloat16* __restrict__ X0b,
    __hip_bfloat16* __restrict__ X1b, long n) {
  long i = (long)blockIdx.x * 256 + threadIdx.x;
  if (i < n) {
    float a = d0[i], b = d1[i];
    outF[i] = a;
    outF[n + i] = b;
    X0b[i] = __float2bfloat16(a);
    X1b[i] = __float2bfloat16(b);
  }
}

// ---------------------------------------------------------------------------
// bf16 MFMA GEMM: C[m][n] = act(sum_k A[m][k]*Bt[n][k] + bias[n]) * rowmask[m]
// A: M x K bf16 row-major.  Bt: N x K bf16 row-major (pre-transposed weights).
// act: 0 none, 1 elu+1, 2 relu.  M=38400 (mult of 128), N,K mult of 128/64.
// ---------------------------------------------------------------------------
#define BM 128
#define BN 128
#define BKK 64
#define LDK 72   // padded LDS k-stride (144 B/row -> 2-way bank alias, free)

__global__ __launch_bounds__(256, 2) void gemm_bt(
    const __hip_bfloat16* __restrict__ A, const __hip_bfloat16* __restrict__ Bt,
    const float* __restrict__ bias, const float* __restrict__ rowmask,
    __hip_bfloat16* __restrict__ C, int M, int Nout, int K, int act) {
  __shared__ alignas(16) __hip_bfloat16 As[BM][LDK];
  __shared__ alignas(16) __hip_bfloat16 Bs[BN][LDK];

  int tid = threadIdx.x;
  int wave = tid >> 6;
  int lane = tid & 63;
  int wm = wave & 1, wn = wave >> 1;     // 2x2 wave grid, each 64x64
  int quad = lane >> 4;                  // 0..3
  int l16 = lane & 15;
  long mbase = (long)blockIdx.y * BM;
  long nbase = (long)blockIdx.x * BN;

  f32x4 acc[4][4];
#pragma unroll
  for (int i = 0; i < 4; i++)
#pragma unroll
    for (int j = 0; j < 4; j++) acc[i][j] = (f32x4){0.f, 0.f, 0.f, 0.f};

  for (int kt = 0; kt < K; kt += BKK) {
    __syncthreads();
    // stage A-tile and B-tile: 128 rows x 64 k each; 16B chunks, 4 per thread
#pragma unroll
    for (int it = 0; it < 4; it++) {
      int idx = tid + it * 256;          // 0..1023
      int row = idx >> 3;
      int ck = idx & 7;
      uint4 va = *(const uint4*)(A + (mbase + row) * (long)K + kt + ck * 8);
      *(uint4*)&As[row][ck * 8] = va;
      uint4 vb = *(const uint4*)(Bt + (nbase + row) * (long)K + kt + ck * 8);
      *(uint4*)&Bs[row][ck * 8] = vb;
    }
    __syncthreads();
#pragma unroll
    for (int ks = 0; ks < BKK; ks += 32) {
      short8 af[4], bfr[4];
#pragma unroll
      for (int mt = 0; mt < 4; mt++)
        af[mt] = *(const short8*)&As[wm * 64 + mt * 16 + l16][ks + quad * 8];
#pragma unroll
      for (int nt = 0; nt < 4; nt++)
        bfr[nt] = *(const short8*)&Bs[wn * 64 + nt * 16 + l16][ks + quad * 8];
#pragma unroll
      for (int mt = 0; mt < 4; mt++)
#pragma unroll
        for (int nt = 0; nt < 4; nt++)
          acc[mt][nt] = __builtin_amdgcn_mfma_f32_16x16x32_bf16(
              af[mt], bfr[nt], acc[mt][nt], 0, 0, 0);
    }
  }

  // epilogue: bias + activation + rowmask, bf16 store
#pragma unroll
  for (int nt = 0; nt < 4; nt++) {
    long col = nbase + wn * 64 + nt * 16 + l16;
    float bv = bias ? bias[col] : 0.0f;
#pragma unroll
    for (int mt = 0; mt < 4; mt++) {
      long row0 = mbase + wm * 64 + mt * 16 + quad * 4;
#pragma unroll
      for (int r = 0; r < 4; r++) {
        long row = row0 + r;
        float v = acc[mt][nt][r] + bv;
        if (act == 1) v = v > 0.f ? v + 1.f : __expf(v);
        else if (act == 2) v = v > 0.f ? v : 0.f;
        if (rowmask) v *= rowmask[row];
        C[row * (long)Nout + col] = __float2bfloat16(v);
      }
    }
  }
}

// ---------------------------------------------------------------------------
// KV reduce: KVws[bh][d][m] += sum_s K[b,s,h,d]*V[b,s,h,m]; Ksum[bh][d] += K.
// Grid (B, H, 10 chunks of 480 rows), 256 threads.
// ---------------------------------------------------------------------------
__global__ __launch_bounds__(256) void kv_reduce(
    const __hip_bfloat16* __restrict__ Kp, const __hip_bfloat16* __restrict__ Vp,
    float* __restrict__ KV, float* __restrict__ Ksum) {
  int b = blockIdx.x, h = blockIdx.y, c = blockIdx.z;
  __shared__ float Kl[8][32], Vl[8][32];
  int t = threadIdx.x;
  int sl = t >> 5, e = t & 31;       // staging: 8 rows x 32 elems
  int d = t >> 3, mg = t & 7;        // compute: d in 0..31, 4 m's per thread
  float accv[4] = {0.f, 0.f, 0.f, 0.f};
  float ksacc = 0.f;
  int s0 = c * 480;
  for (int s = s0; s < s0 + 480; s += 8) {
    long n = (long)b * LSEQ + s + sl;
    Kl[sl][e] = __bfloat162float(Kp[n * 256 + h * 32 + e]);
    Vl[sl][e] = __bfloat162float(Vp[n * 256 + h * 32 + e]);
    __syncthreads();
#pragma unroll
    for (int ss = 0; ss < 8; ss++) {
      float kd = Kl[ss][d];
#pragma unroll
      for (int j = 0; j < 4; j++) accv[j] += kd * Vl[ss][mg * 4 + j];
      if (mg == 0) ksacc += kd;
    }
    __syncthreads();
  }
  int bh = b * 8 + h;
  float* KVp2 = KV + ((long)bh * 32 + d) * 32 + mg * 4;
#pragma unroll
  for (int j = 0; j < 4; j++) atomicAdd(&KVp2[j], accv[j]);
  if (mg == 0) atomicAdd(&Ksum[bh * 32 + d], ksacc);
}

// ---------------------------------------------------------------------------
// Attention output: O[n, h*32+m] = (sum_d Q[d]*KV[h][d][m]) / (Q.Ksum[h] + eps)
// Grid (150 l-chunks, B), 256 threads; 32 rows per block.
// ---------------------------------------------------------------------------
__global__ __launch_bounds__(256) void attn_out(
    const __hip_bfloat16* __restrict__ Qp, const float* __restrict__ KV,
    const float* __restrict__ Ksum, __hip_bfloat16* __restrict__ O) {
  int lc = blockIdx.x, b = blockIdx.y;
  __shared__ float KVl[8][32][32];
  __shared__ float KSl[8][32];
  __shared__ float ql[256];
  int t = threadIdx.x;
  for (int i = t; i < 8 * 32 * 32; i += 256)
    ((float*)KVl)[i] = KV[(long)b * 8192 + i];
  ((float*)KSl)[t] = Ksum[b * 256 + t];
  __syncthreads();
  int h = t >> 5, m = t & 31;
  for (int r = 0; r < 32; r++) {
    long n = (long)b * LSEQ + lc * 32 + r;
    ql[t] = __bfloat162float(Qp[n * 256 + t]);
    __syncthreads();
    float s1 = 0.f, den = 0.f;
#pragma unroll
    for (int d = 0; d < 32; d++) {
      float qd = ql[h * 32 + d];
      s1 += qd * KVl[h][d][m];
      den += qd * KSl[h][d];
    }
    O[n * 256 + t] = __float2bfloat16(s1 / (den + 1e-6f));
    __syncthreads();
  }
}

// ---------------------------------------------------------------------------
// LayerNorm in-place on bf16 rows of 256. 4 rows/block (wave per row).
// ---------------------------------------------------------------------------
__global__ __launch_bounds__(256) void ln_kernel(
    __hip_bfloat16* __restrict__ X, const float* __restrict__ g,
    const float* __restrict__ bt) {
  int wave = threadIdx.x >> 6, lane = threadIdx.x & 63;
  long row = (long)blockIdx.x * 4 + wave;
  __hip_bfloat16* p = X + row * 256 + lane * 4;
  ushort4 u = *(const ushort4*)p;
  float v[4];
  v[0] = __bfloat162float(*(__hip_bfloat16*)&u.x);
  v[1] = __bfloat162float(*(__hip_bfloat16*)&u.y);
  v[2] = __bfloat162float(*(__hip_bfloat16*)&u.z);
  v[3] = __bfloat162float(*(__hip_bfloat16*)&u.w);
  float s = v[0] + v[1] + v[2] + v[3];
  float s2 = v[0] * v[0] + v[1] * v[1] + v[2] * v[2] + v[3] * v[3];
#pragma unroll
  for (int off = 32; off; off >>= 1) {
    s += __shfl_xor(s, off);
    s2 += __shfl_xor(s2, off);
  }
  float mu = s * (1.f / 256.f);
  float var = s2 * (1.f / 256.f) - mu * mu;
  float rs = rsqrtf(var + 1e-5f);
  __hip_bfloat16 o[4];
#pragma unroll
  for (int j = 0; j < 4; j++) {
    int cc = lane * 4 + j;
    o[j] = __float2bfloat16((v[j] - mu) * rs * g[cc] + bt[cc]);
  }
  *(ushort4*)p = *(ushort4*)o;
}

// ---------------------------------------------------------------------------
// Final: LN(M2) + residual; writes fp32 residual stream and bf16 mirror.
// ---------------------------------------------------------------------------
__global__ __launch_bounds__(256) void final_kernel(
    const __hip_bfloat16* __restrict__ M2, const float* __restrict__ g,
    const float* __restrict__ bt, float* __restrict__ outF,
    __hip_bfloat16* __restrict__ Xb) {
  int wave = threadIdx.x >> 6, lane = threadIdx.x & 63;
  long row = (long)blockIdx.x * 4 + wave;
  const __hip_bfloat16* p = M2 + row * 256 + lane * 4;
  ushort4 u = *(const ushort4*)p;
  float v[4];
  v[0] = __bfloat162float(*(__hip_bfloat16*)&u.x);
  v[1] = __bfloat162float(*(__hip_bfloat16*)&u.y);
  v[2] = __bfloat162float(*(__hip_bfloat16*)&u.z);
  v[3] = __bfloat162float(*(__hip_bfloat16*)&u.w);
  float s = v[0] + v[1] + v[2] + v[3];
  float s2 = v[0] * v[0] + v[1] * v[1] + v[2] * v[2] + v[3] * v[3];
#pragma unroll
  for (int off = 32; off; off >>= 1) {
    s += __shfl_xor(s, off);
    s2 += __shfl_xor(s2, off);
  }
  float mu = s * (1.f / 256.f);
  float var = s2 * (1.f / 256.f) - mu * mu;
  float rs = rsqrtf(var + 1e-5f);
  float* op = outF + row * 256 + lane * 4;
  __hip_bfloat16 xb[4];
  float r4[4];
#pragma unroll
  for (int j = 0; j < 4; j++) {
    int cc = lane * 4 + j;
    float ln = (v[j] - mu) * rs * g[cc] + bt[cc];
    r4[j] = op[j] + ln;
    xb[j] = __float2bfloat16(r4[j]);
  }
  *(float4*)op = *(float4*)r4;
  *(ushort4*)(Xb + row * 256 + lane * 4) = *(ushort4*)xb;
}

// ---------------------------------------------------------------------------
extern "C" void kernel_launch(void* const* d_in, const int* in_sizes, int n_in,
                              void* d_out, int out_size, void* d_ws, size_t ws_size,
                              hipStream_t stream) {
  const float* desc0 = (const float*)d_in[0];
  const float* desc1 = (const float*)d_in[1];
  const float* mask0 = (const float*)d_in[2];
  const float* mask1 = (const float*)d_in[3];
  const float* Wq = (const float*)d_in[4];
  const float* bq = (const float*)d_in[5];
  const float* Wk = (const float*)d_in[6];
  const float* bk = (const float*)d_in[7];
  const float* Wv = (const float*)d_in[8];
  const float* bv = (const float*)d_in[9];
  const float* Wm = (const float*)d_in[10];
  const float* bm = (const float*)d_in[11];
  const float* w1 = (const float*)d_in[12];
  const float* w2 = (const float*)d_in[13];
  const float* g1 = (const float*)d_in[14];
  const float* b1 = (const float*)d_in[15];
  const float* g2 = (const float*)d_in[16];
  const float* b2 = (const float*)d_in[17];

  char* ws = (char*)d_ws;
  auto alloc = [&](size_t bytes) {
    char* p = ws;
    ws += (bytes + 255) & ~(size_t)255;
    return p;
  };
  __hip_bfloat16* WqT = (__hip_bfloat16*)alloc(256 * 256 * 2);
  __hip_bfloat16* WkT = (__hip_bfloat16*)alloc(256 * 256 * 2);
  __hip_bfloat16* WvT = (__hip_bfloat16*)alloc(256 * 256 * 2);
  __hip_bfloat16* WmT = (__hip_bfloat16*)alloc(256 * 256 * 2);
  __hip_bfloat16* w1T = (__hip_bfloat16*)alloc((size_t)8 * 512 * 256 * 2);
  __hip_bfloat16* w2T = (__hip_bfloat16*)alloc((size_t)8 * 256 * 512 * 2);
  __hip_bfloat16* X0b = (__hip_bfloat16*)alloc((size_t)NROWS * 256 * 2);
  __hip_bfloat16* X1b = (__hip_bfloat16*)alloc((size_t)NROWS * 256 * 2);
  __hip_bfloat16* Qb = (__hip_bfloat16*)alloc((size_t)NROWS * 256 * 2);
  __hip_bfloat16* Kb = (__hip_bfloat16*)alloc((size_t)NROWS * 256 * 2);
  __hip_bfloat16* Vb = (__hip_bfloat16*)alloc((size_t)NROWS * 256 * 2);
  __hip_bfloat16* Ab = (__hip_bfloat16*)alloc((size_t)NROWS * 256 * 2);
  __hip_bfloat16* H1b = (__hip_bfloat16*)alloc((size_t)NROWS * 512 * 2);
  float* KVws = (float*)alloc((64 * 1024 + 64 * 32) * 4);
  float* Ksum = KVws + 64 * 1024;

  // weight prep (same work every call)
  transpose_bf16<<<dim3(8, 8), 256, 0, stream>>>(Wq, WqT, 256, 256);
  transpose_bf16<<<dim3(8, 8), 256, 0, stream>>>(Wk, WkT, 256, 256);
  transpose_bf16<<<dim3(8, 8), 256, 0, stream>>>(Wv, WvT, 256, 256);
  transpose_bf16<<<dim3(8, 8), 256, 0, stream>>>(Wm, WmT, 256, 256);
  for (int i = 0; i < 8; i++) {
    transpose_bf16<<<dim3(16, 8), 256, 0, stream>>>(
        w1 + (size_t)i * 256 * 512, w1T + (size_t)i * 512 * 256, 256, 512);
    transpose_bf16<<<dim3(8, 16), 256, 0, stream>>>(
        w2 + (size_t)i * 512 * 256, w2T + (size_t)i * 256 * 512, 512, 256);
  }

  long nElem = (long)NROWS * 256;
  init_x<<<(nElem + 255) / 256, 256, 0, stream>>>(desc0, desc1, (float*)d_out,
                                                  X0b, X1b, nElem);

  auto gemm = [&](const __hip_bfloat16* A, const __hip_bfloat16* Bt,
                  const float* bias, const float* rm, __hip_bfloat16* C,
                  int Nout, int K, int act) {
    dim3 grid(Nout / BN, NROWS / BM);
    gemm_bt<<<grid, 256, 0, stream>>>(A, Bt, bias, rm, C, NROWS, Nout, K, act);
  };

  auto layer = [&](int x, int s, int i) {
    __hip_bfloat16* Xx = x ? X1b : X0b;
    __hip_bfloat16* Xs = s ? X1b : X0b;
    const float* mx = x ? mask1 : mask0;
    const float* ms = s ? mask1 : mask0;
    gemm(Xx, WqT, bq, mx, Qb, 256, 256, 1);            // Q = elu+1, *qmask
    gemm(Xs, WkT, bk, ms, Kb, 256, 256, 1);            // K = elu+1, *kmask
    gemm(Xs, WvT, bv, ms, Vb, 256, 256, 0);            // V = *kmask
    hipMemsetAsync(KVws, 0, (64 * 1024 + 64 * 32) * 4, stream);
    kv_reduce<<<dim3(BATCH, NHEAD, 10), 256, 0, stream>>>(Kb, Vb, KVws, Ksum);
    attn_out<<<dim3(150, BATCH), 256, 0, stream>>>(Qb, KVws, Ksum, Ab);
    gemm(Ab, WmT, bm, nullptr, Kb, 256, 256, 0);       // msg = A@Wm + bm (into Kb)
    ln_kernel<<<NROWS / 4, 256, 0, stream>>>(Kb, g1 + i * 256, b1 + i * 256);
    gemm(Kb, w1T + (size_t)i * 512 * 256, nullptr, nullptr, H1b, 512, 256, 2);
    gemm(H1b, w2T + (size_t)i * 256 * 512, nullptr, nullptr, Vb, 256, 512, 0);
    final_kernel<<<NROWS / 4, 256, 0, stream>>>(
        Vb, g2 + i * 256, b2 + i * 256, (float*)d_out + (size_t)x * nElem, Xx);
  };

  for (int i = 0; i < 8; i++) {
    if (i % 2 == 0) {        // self
      layer(0, 0, i);
      layer(1, 1, i);
    } else {                 // cross (desc1 sees UPDATED desc0)
      layer(0, 1, i);
      layer(1, 0, i);
    }
  }
}

// Round 5
// 3796.094 us; speedup vs baseline: 1.2280x; 1.2280x over previous
//
#include <hip/hip_runtime.h>
#include <hip/hip_bf16.h>

typedef __attribute__((ext_vector_type(8))) short short8;
typedef __attribute__((ext_vector_type(4))) float f32x4;

#define NROWS 38400      // B*L = 8*4800
#define LSEQ 4800
#define BATCH 8
#define NHEAD 8

__device__ inline float b2f(ushort u) {
  union { ushort s; __hip_bfloat16 h; } c;
  c.s = u;
  return __bfloat162float(c.h);
}
__device__ inline ushort f2b(float f) {
  union { ushort s; __hip_bfloat16 h; } c;
  c.h = __float2bfloat16(f);
  return c.s;
}

// ---------------------------------------------------------------------------
// Tiled transpose + fp32->bf16: dst[c][r] = src[r][c], batched over blockIdx.z.
// ---------------------------------------------------------------------------
__global__ __launch_bounds__(256) void transpose_bf16(
    const float* __restrict__ src, __hip_bfloat16* __restrict__ dst, int R, int C) {
  src += (size_t)blockIdx.z * R * C;
  dst += (size_t)blockIdx.z * R * C;
  __shared__ float tile[32][33];
  int bx = blockIdx.x, by = blockIdx.y;
  int tx = threadIdx.x & 31, ty = threadIdx.x >> 5;
  for (int rr = ty; rr < 32; rr += 8)
    tile[rr][tx] = src[(long)(by * 32 + rr) * C + bx * 32 + tx];
  __syncthreads();
  for (int rr = ty; rr < 32; rr += 8)
    dst[(long)(bx * 32 + rr) * R + by * 32 + tx] = __float2bfloat16(tile[tx][rr]);
}

// ---------------------------------------------------------------------------
__global__ __launch_bounds__(256) void init_x(
    const float* __restrict__ d0, const float* __restrict__ d1,
    float* __restrict__ outF, __hip_bfloat16* __restrict__ X0b,
    __hip_bfloat16* __restrict__ X1b, long n) {
  long i = (long)blockIdx.x * 256 + threadIdx.x;
  if (i < n) {
    float a = d0[i], b = d1[i];
    outF[i] = a;
    outF[n + i] = b;
    X0b[i] = __float2bfloat16(a);
    X1b[i] = __float2bfloat16(b);
  }
}

// ---------------------------------------------------------------------------
// bf16 MFMA GEMM (R1-proven version: padded LDS, vector-register staging).
// C[m][n] = act(sum_k A[m][k]*Bt[n][k] + bias[n]) * rowmask[m]
// ---------------------------------------------------------------------------
#define BM 128
#define BN 128
#define BKK 64
#define LDK 72   // padded LDS k-stride (144 B/row -> 2-way bank alias, free)

__global__ __launch_bounds__(256, 2) void gemm_bt(
    const __hip_bfloat16* __restrict__ A, const __hip_bfloat16* __restrict__ Bt,
    const float* __restrict__ bias, const float* __restrict__ rowmask,
    __hip_bfloat16* __restrict__ C, int M, int Nout, int K, int act) {
  __shared__ alignas(16) __hip_bfloat16 As[BM][LDK];
  __shared__ alignas(16) __hip_bfloat16 Bs[BN][LDK];

  int tid = threadIdx.x;
  int wave = tid >> 6;
  int lane = tid & 63;
  int wm = wave & 1, wn = wave >> 1;     // 2x2 wave grid, each 64x64
  int quad = lane >> 4;                  // 0..3
  int l16 = lane & 15;
  long mbase = (long)blockIdx.y * BM;
  long nbase = (long)blockIdx.x * BN;

  f32x4 acc[4][4];
#pragma unroll
  for (int i = 0; i < 4; i++)
#pragma unroll
    for (int j = 0; j < 4; j++) acc[i][j] = (f32x4){0.f, 0.f, 0.f, 0.f};

  for (int kt = 0; kt < K; kt += BKK) {
    __syncthreads();
#pragma unroll
    for (int it = 0; it < 4; it++) {
      int idx = tid + it * 256;          // 0..1023
      int row = idx >> 3;
      int ck = idx & 7;
      uint4 va = *(const uint4*)(A + (mbase + row) * (long)K + kt + ck * 8);
      *(uint4*)&As[row][ck * 8] = va;
      uint4 vb = *(const uint4*)(Bt + (nbase + row) * (long)K + kt + ck * 8);
      *(uint4*)&Bs[row][ck * 8] = vb;
    }
    __syncthreads();
#pragma unroll
    for (int ks = 0; ks < BKK; ks += 32) {
      short8 af[4], bfr[4];
#pragma unroll
      for (int mt = 0; mt < 4; mt++)
        af[mt] = *(const short8*)&As[wm * 64 + mt * 16 + l16][ks + quad * 8];
#pragma unroll
      for (int nt = 0; nt < 4; nt++)
        bfr[nt] = *(const short8*)&Bs[wn * 64 + nt * 16 + l16][ks + quad * 8];
#pragma unroll
      for (int mt = 0; mt < 4; mt++)
#pragma unroll
        for (int nt = 0; nt < 4; nt++)
          acc[mt][nt] = __builtin_amdgcn_mfma_f32_16x16x32_bf16(
              af[mt], bfr[nt], acc[mt][nt], 0, 0, 0);
    }
  }

  // epilogue: bias + activation + rowmask, bf16 store
#pragma unroll
  for (int nt = 0; nt < 4; nt++) {
    long col = nbase + wn * 64 + nt * 16 + l16;
    float bv = bias ? bias[col] : 0.0f;
#pragma unroll
    for (int mt = 0; mt < 4; mt++) {
      long row0 = mbase + wm * 64 + mt * 16 + quad * 4;
#pragma unroll
      for (int r = 0; r < 4; r++) {
        long row = row0 + r;
        float v = acc[mt][nt][r] + bv;
        if (act == 1) v = v > 0.f ? v + 1.f : __expf(v);
        else if (act == 2) v = v > 0.f ? v : 0.f;
        if (rowmask) v *= rowmask[row];
        C[row * (long)Nout + col] = __float2bfloat16(v);
      }
    }
  }
}

// ---------------------------------------------------------------------------
// KV reduce: KV[bh][d][m] += sum_s K[b,s,h,d]*V[b,s,h,m]; Ksum[bh][d] += K.
// Grid (B, H, 10), 256 threads, 32-row stages (15 barrier pairs).
// ---------------------------------------------------------------------------
__global__ __launch_bounds__(256) void kv_reduce(
    const __hip_bfloat16* __restrict__ Kp, const __hip_bfloat16* __restrict__ Vp,
    float* __restrict__ KV, float* __restrict__ Ksum) {
  int b = blockIdx.x, h = blockIdx.y, c = blockIdx.z;
  __shared__ float Kl[32][40], Vl[32][40];   // stride 40: 16B-aligned, 2-way free
  int t = threadIdx.x;
  int lrow = t >> 3, le = (t & 7) * 4;       // staging: 32 rows x 32 elems, 4/thread
  int d = t >> 3, mg = t & 7;                // compute mapping
  float a0 = 0.f, a1 = 0.f, a2 = 0.f, a3 = 0.f, ks = 0.f;
  int base = c * 480;
  for (int st = 0; st < 15; st++) {
    int s0 = base + st * 32;
    __syncthreads();
    {
      long n = (long)b * LSEQ + s0 + lrow;
      ushort4 ku = *(const ushort4*)(Kp + n * 256 + h * 32 + le);
      ushort4 vu = *(const ushort4*)(Vp + n * 256 + h * 32 + le);
      float4 kf = {b2f(ku.x), b2f(ku.y), b2f(ku.z), b2f(ku.w)};
      float4 vf = {b2f(vu.x), b2f(vu.y), b2f(vu.z), b2f(vu.w)};
      *(float4*)&Kl[lrow][le] = kf;
      *(float4*)&Vl[lrow][le] = vf;
    }
    __syncthreads();
#pragma unroll
    for (int ss = 0; ss < 32; ss++) {
      float kd = Kl[ss][d];
      float4 v4 = *(const float4*)&Vl[ss][mg * 4];
      a0 += kd * v4.x; a1 += kd * v4.y; a2 += kd * v4.z; a3 += kd * v4.w;
      if (mg == 0) ks += kd;
    }
  }
  int bh = b * 8 + h;
  float* p = KV + ((long)bh * 32 + d) * 32 + mg * 4;
  atomicAdd(&p[0], a0); atomicAdd(&p[1], a1);
  atomicAdd(&p[2], a2); atomicAdd(&p[3], a3);
  if (mg == 0) atomicAdd(&Ksum[bh * 32 + d], ks);
}

// ---------------------------------------------------------------------------
// Attention output, barrier-free main loop, pure-register q broadcast (shfl).
// Grid (25, B, H); 4 waves; wave handles 8 rows/pass, lane = (rowsub, 4 cols).
// O[n, h*32+m] = (sum_d Q[d]*KV[h][d][m]) / (Q . Ksum[h] + eps)
// ---------------------------------------------------------------------------
__global__ __launch_bounds__(256) void attn_out(
    const __hip_bfloat16* __restrict__ Qp, const float* __restrict__ KV,
    const float* __restrict__ Ksum, __hip_bfloat16* __restrict__ O) {
  int b = blockIdx.y, h = blockIdx.z;
  int bh = b * 8 + h;
  __shared__ float KVl[32][36];        // [d][m], stride 36: 16B-aligned
  int t = threadIdx.x;
  for (int i = t; i < 1024; i += 256) KVl[i >> 5][i & 31] = KV[((long)bh << 10) + i];
  int lane = t & 63, wave = t >> 6;
  int cg = lane & 7, rs = lane >> 3;
  float4 ksr = *(const float4*)&Ksum[bh * 32 + cg * 4];
  __syncthreads();

  int rowEnd = blockIdx.x * 192 + 192;
  for (int r = blockIdx.x * 192 + wave * 8 + rs; r < rowEnd; r += 32) {
    long n = (long)b * LSEQ + r;
    ushort4 qu = *(const ushort4*)(Qp + n * 256 + h * 32 + cg * 4);
    float q0 = b2f(qu.x), q1 = b2f(qu.y), q2 = b2f(qu.z), q3 = b2f(qu.w);
    // denominator: partial dot with Ksum, reduce over the 8-lane row group
    float den = q0 * ksr.x + q1 * ksr.y + q2 * ksr.z + q3 * ksr.w;
    den += __shfl_xor(den, 1);
    den += __shfl_xor(den, 2);
    den += __shfl_xor(den, 4);
    // numerator: broadcast each group's q chunk via shfl (no LDS, no barrier)
    float s0 = 0.f, s1 = 0.f, s2 = 0.f, s3 = 0.f;
    int gbase = lane & ~7;             // first lane of this row group
#pragma unroll
    for (int j = 0; j < 8; j++) {
      int src = gbase | j;             // lane holding q[d=4j..4j+3]
      float qa = __shfl(q0, src);
      float qb = __shfl(q1, src);
      float qc = __shfl(q2, src);
      float qd = __shfl(q3, src);
      float4 k0 = *(const float4*)&KVl[j * 4 + 0][cg * 4];
      float4 k1 = *(const float4*)&KVl[j * 4 + 1][cg * 4];
      float4 k2 = *(const float4*)&KVl[j * 4 + 2][cg * 4];
      float4 k3 = *(const float4*)&KVl[j * 4 + 3][cg * 4];
      s0 += qa * k0.x + qb * k1.x + qc * k2.x + qd * k3.x;
      s1 += qa * k0.y + qb * k1.y + qc * k2.y + qd * k3.y;
      s2 += qa * k0.z + qb * k1.z + qc * k2.z + qd * k3.z;
      s3 += qa * k0.w + qb * k1.w + qc * k2.w + qd * k3.w;
    }
    float inv = 1.0f / (den + 1e-6f);
    ushort4 ou = {f2b(s0 * inv), f2b(s1 * inv), f2b(s2 * inv), f2b(s3 * inv)};
    *(ushort4*)(O + n * 256 + h * 32 + cg * 4) = ou;
  }
}

// ---------------------------------------------------------------------------
// LayerNorm in-place on bf16 rows of 256. 4 rows/block (wave per row).
// ---------------------------------------------------------------------------
__global__ __launch_bounds__(256) void ln_kernel(
    __hip_bfloat16* __restrict__ X, const float* __restrict__ g,
    const float* __restrict__ bt) {
  int wave = threadIdx.x >> 6, lane = threadIdx.x & 63;
  long row = (long)blockIdx.x * 4 + wave;
  __hip_bfloat16* p = X + row * 256 + lane * 4;
  ushort4 u = *(const ushort4*)p;
  float v[4] = {b2f(u.x), b2f(u.y), b2f(u.z), b2f(u.w)};
  float s = v[0] + v[1] + v[2] + v[3];
  float s2 = v[0] * v[0] + v[1] * v[1] + v[2] * v[2] + v[3] * v[3];
#pragma unroll
  for (int off = 32; off; off >>= 1) {
    s += __shfl_xor(s, off);
    s2 += __shfl_xor(s2, off);
  }
  float mu = s * (1.f / 256.f);
  float var = s2 * (1.f / 256.f) - mu * mu;
  float rs = rsqrtf(var + 1e-5f);
  ushort4 o;
  o.x = f2b((v[0] - mu) * rs * g[lane * 4 + 0] + bt[lane * 4 + 0]);
  o.y = f2b((v[1] - mu) * rs * g[lane * 4 + 1] + bt[lane * 4 + 1]);
  o.z = f2b((v[2] - mu) * rs * g[lane * 4 + 2] + bt[lane * 4 + 2]);
  o.w = f2b((v[3] - mu) * rs * g[lane * 4 + 3] + bt[lane * 4 + 3]);
  *(ushort4*)p = o;
}

// ---------------------------------------------------------------------------
// Final: LN(M2) + residual; writes fp32 residual stream and bf16 mirror.
// ---------------------------------------------------------------------------
__global__ __launch_bounds__(256) void final_kernel(
    const __hip_bfloat16* __restrict__ M2, const float* __restrict__ g,
    const float* __restrict__ bt, float* __restrict__ outF,
    __hip_bfloat16* __restrict__ Xb) {
  int wave = threadIdx.x >> 6, lane = threadIdx.x & 63;
  long row = (long)blockIdx.x * 4 + wave;
  const __hip_bfloat16* p = M2 + row * 256 + lane * 4;
  ushort4 u = *(const ushort4*)p;
  float v[4] = {b2f(u.x), b2f(u.y), b2f(u.z), b2f(u.w)};
  float s = v[0] + v[1] + v[2] + v[3];
  float s2 = v[0] * v[0] + v[1] * v[1] + v[2] * v[2] + v[3] * v[3];
#pragma unroll
  for (int off = 32; off; off >>= 1) {
    s += __shfl_xor(s, off);
    s2 += __shfl_xor(s2, off);
  }
  float mu = s * (1.f / 256.f);
  float var = s2 * (1.f / 256.f) - mu * mu;
  float rs = rsqrtf(var + 1e-5f);
  float* op = outF + row * 256 + lane * 4;
  float4 rv = *(float4*)op;
  float r0 = rv.x + ((v[0] - mu) * rs * g[lane * 4 + 0] + bt[lane * 4 + 0]);
  float r1 = rv.y + ((v[1] - mu) * rs * g[lane * 4 + 1] + bt[lane * 4 + 1]);
  float r2 = rv.z + ((v[2] - mu) * rs * g[lane * 4 + 2] + bt[lane * 4 + 2]);
  float r3 = rv.w + ((v[3] - mu) * rs * g[lane * 4 + 3] + bt[lane * 4 + 3]);
  *(float4*)op = (float4){r0, r1, r2, r3};
  ushort4 xb = {f2b(r0), f2b(r1), f2b(r2), f2b(r3)};
  *(ushort4*)(Xb + row * 256 + lane * 4) = xb;
}

// ---------------------------------------------------------------------------
extern "C" void kernel_launch(void* const* d_in, const int* in_sizes, int n_in,
                              void* d_out, int out_size, void* d_ws, size_t ws_size,
                              hipStream_t stream) {
  const float* desc0 = (const float*)d_in[0];
  const float* desc1 = (const float*)d_in[1];
  const float* mask0 = (const float*)d_in[2];
  const float* mask1 = (const float*)d_in[3];
  const float* Wq = (const float*)d_in[4];
  const float* bq = (const float*)d_in[5];
  const float* Wk = (const float*)d_in[6];
  const float* bk = (const float*)d_in[7];
  const float* Wv = (const float*)d_in[8];
  const float* bv = (const float*)d_in[9];
  const float* Wm = (const float*)d_in[10];
  const float* bm = (const float*)d_in[11];
  const float* w1 = (const float*)d_in[12];
  const float* w2 = (const float*)d_in[13];
  const float* g1 = (const float*)d_in[14];
  const float* b1 = (const float*)d_in[15];
  const float* g2 = (const float*)d_in[16];
  const float* b2 = (const float*)d_in[17];

  char* ws = (char*)d_ws;
  auto alloc = [&](size_t bytes) {
    char* p = ws;
    ws += (bytes + 255) & ~(size_t)255;
    return p;
  };
  __hip_bfloat16* WqT = (__hip_bfloat16*)alloc(256 * 256 * 2);
  __hip_bfloat16* WkT = (__hip_bfloat16*)alloc(256 * 256 * 2);
  __hip_bfloat16* WvT = (__hip_bfloat16*)alloc(256 * 256 * 2);
  __hip_bfloat16* WmT = (__hip_bfloat16*)alloc(256 * 256 * 2);
  __hip_bfloat16* w1T = (__hip_bfloat16*)alloc((size_t)8 * 512 * 256 * 2);
  __hip_bfloat16* w2T = (__hip_bfloat16*)alloc((size_t)8 * 256 * 512 * 2);
  __hip_bfloat16* X0b = (__hip_bfloat16*)alloc((size_t)NROWS * 256 * 2);
  __hip_bfloat16* X1b = (__hip_bfloat16*)alloc((size_t)NROWS * 256 * 2);
  __hip_bfloat16* Qb = (__hip_bfloat16*)alloc((size_t)NROWS * 256 * 2);
  __hip_bfloat16* Kb = (__hip_bfloat16*)alloc((size_t)NROWS * 256 * 2);
  __hip_bfloat16* Vb = (__hip_bfloat16*)alloc((size_t)NROWS * 256 * 2);
  __hip_bfloat16* Ab = (__hip_bfloat16*)alloc((size_t)NROWS * 256 * 2);
  __hip_bfloat16* H1b = (__hip_bfloat16*)alloc((size_t)NROWS * 512 * 2);
  float* KVws = (float*)alloc((64 * 1024 + 64 * 32) * 4);
  float* Ksum = KVws + 64 * 1024;

  // weight prep (batched)
  transpose_bf16<<<dim3(8, 8, 1), 256, 0, stream>>>(Wq, WqT, 256, 256);
  transpose_bf16<<<dim3(8, 8, 1), 256, 0, stream>>>(Wk, WkT, 256, 256);
  transpose_bf16<<<dim3(8, 8, 1), 256, 0, stream>>>(Wv, WvT, 256, 256);
  transpose_bf16<<<dim3(8, 8, 1), 256, 0, stream>>>(Wm, WmT, 256, 256);
  transpose_bf16<<<dim3(16, 8, 8), 256, 0, stream>>>(w1, w1T, 256, 512);
  transpose_bf16<<<dim3(8, 16, 8), 256, 0, stream>>>(w2, w2T, 512, 256);

  long nElem = (long)NROWS * 256;
  init_x<<<(nElem + 255) / 256, 256, 0, stream>>>(desc0, desc1, (float*)d_out,
                                                  X0b, X1b, nElem);

  auto gemm = [&](const __hip_bfloat16* A, const __hip_bfloat16* Bt,
                  const float* bias, const float* rm, __hip_bfloat16* C,
                  int Nout, int K, int act) {
    dim3 grid(Nout / BN, NROWS / BM);
    gemm_bt<<<grid, 256, 0, stream>>>(A, Bt, bias, rm, C, NROWS, Nout, K, act);
  };

  auto layer = [&](int x, int s, int i) {
    __hip_bfloat16* Xx = x ? X1b : X0b;
    __hip_bfloat16* Xs = s ? X1b : X0b;
    const float* mx = x ? mask1 : mask0;
    const float* ms = s ? mask1 : mask0;
    gemm(Xx, WqT, bq, mx, Qb, 256, 256, 1);            // Q = elu+1, *qmask
    gemm(Xs, WkT, bk, ms, Kb, 256, 256, 1);            // K = elu+1, *kmask
    gemm(Xs, WvT, bv, ms, Vb, 256, 256, 0);            // V = *kmask
    hipMemsetAsync(KVws, 0, (64 * 1024 + 64 * 32) * 4, stream);
    kv_reduce<<<dim3(BATCH, NHEAD, 10), 256, 0, stream>>>(Kb, Vb, KVws, Ksum);
    attn_out<<<dim3(25, BATCH, NHEAD), 256, 0, stream>>>(Qb, KVws, Ksum, Ab);
    gemm(Ab, WmT, bm, nullptr, Kb, 256, 256, 0);       // msg (into Kb)
    ln_kernel<<<NROWS / 4, 256, 0, stream>>>(Kb, g1 + i * 256, b1 + i * 256);
    gemm(Kb, w1T + (size_t)i * 512 * 256, nullptr, nullptr, H1b, 512, 256, 2);
    gemm(H1b, w2T + (size_t)i * 256 * 512, nullptr, nullptr, Vb, 256, 512, 0);
    final_kernel<<<NROWS / 4, 256, 0, stream>>>(
        Vb, g2 + i * 256, b2 + i * 256, (float*)d_out + (size_t)x * nElem, Xx);
  };

  for (int i = 0; i < 8; i++) {
    if (i % 2 == 0) {        // self
      layer(0, 0, i);
      layer(1, 1, i);
    } else {                 // cross (desc1 sees UPDATED desc0)
      layer(0, 1, i);
      layer(1, 0, i);
    }
  }
}

// Round 6
// 3549.416 us; speedup vs baseline: 1.3133x; 1.0695x over previous
//
#include <hip/hip_runtime.h>
#include <hip/hip_bf16.h>

typedef __attribute__((ext_vector_type(8))) short short8;
typedef __attribute__((ext_vector_type(4))) float f32x4;

#define NROWS 38400      // B*L = 8*4800
#define LSEQ 4800
#define BATCH 8
#define NHEAD 8

__device__ inline float b2f(ushort u) {
  union { ushort s; __hip_bfloat16 h; } c;
  c.s = u;
  return __bfloat162float(c.h);
}
__device__ inline ushort f2b(float f) {
  union { ushort s; __hip_bfloat16 h; } c;
  c.h = __float2bfloat16(f);
  return c.s;
}

// async global->LDS, 16B per lane. LDS dst = wave-uniform base + lane*16.
__device__ inline void gll16(const void* g, void* l) {
  __builtin_amdgcn_global_load_lds(
      (const __attribute__((address_space(1))) void*)g,
      (__attribute__((address_space(3))) void*)l, 16, 0, 0);
}

// ---------------------------------------------------------------------------
// Tiled transpose + fp32->bf16: dst[c][r] = src[r][c], batched over blockIdx.z.
// ---------------------------------------------------------------------------
__global__ __launch_bounds__(256) void transpose_bf16(
    const float* __restrict__ src, __hip_bfloat16* __restrict__ dst, int R, int C) {
  src += (size_t)blockIdx.z * R * C;
  dst += (size_t)blockIdx.z * R * C;
  __shared__ float tile[32][33];
  int bx = blockIdx.x, by = blockIdx.y;
  int tx = threadIdx.x & 31, ty = threadIdx.x >> 5;
  for (int rr = ty; rr < 32; rr += 8)
    tile[rr][tx] = src[(long)(by * 32 + rr) * C + bx * 32 + tx];
  __syncthreads();
  for (int rr = ty; rr < 32; rr += 8)
    dst[(long)(bx * 32 + rr) * R + by * 32 + tx] = __float2bfloat16(tile[tx][rr]);
}

// ---------------------------------------------------------------------------
__global__ __launch_bounds__(256) void init_x(
    const float* __restrict__ d0, const float* __restrict__ d1,
    float* __restrict__ outF, __hip_bfloat16* __restrict__ X0b,
    __hip_bfloat16* __restrict__ X1b, long n) {
  long i = (long)blockIdx.x * 256 + threadIdx.x;
  if (i < n) {
    float a = d0[i], b = d1[i];
    outF[i] = a;
    outF[n + i] = b;
    X0b[i] = __float2bfloat16(a);
    X1b[i] = __float2bfloat16(b);
  }
}

// ---------------------------------------------------------------------------
// bf16 MFMA GEMM, m97-style: global_load_lds width-16 staging, XOR-swizzled
// unpadded LDS tiles, LDS-transposed coalesced epilogue.
// C[m][n] = act(sum_k A[m][k]*Bt[n][k] + bias[n]) * rowmask[m]
// ---------------------------------------------------------------------------
#define BM 128
#define BN 128
#define BKK 64

__global__ __launch_bounds__(256) void gemm_bt(
    const __hip_bfloat16* __restrict__ A, const __hip_bfloat16* __restrict__ Bt,
    const float* __restrict__ bias, const float* __restrict__ rowmask,
    __hip_bfloat16* __restrict__ C, int M, int Nout, int K, int act) {
  // As[128][64] + Bs[128][64] (32 KB) overlap with Cs[128][136] (34 KB)
  __shared__ alignas(16) char smem[128 * 136 * 2];
  __hip_bfloat16 (*As)[64] = (__hip_bfloat16(*)[64])smem;
  __hip_bfloat16 (*Bs)[64] = (__hip_bfloat16(*)[64])(smem + 128 * 64 * 2);
  ushort (*Cs)[136] = (ushort(*)[136])smem;

  int tid = threadIdx.x;
  int wave = tid >> 6, lane = tid & 63;
  int wm = wave & 1, wn = wave >> 1;
  int quad = lane >> 4, l16 = lane & 15;
  long mbase = (long)blockIdx.y * BM;
  long nbase = (long)blockIdx.x * BN;

  // staging: per lane loads 16B; row-sub = lane>>3, global chunk XOR-swizzled
  int srow = lane >> 3;               // 0..7
  int sck = (lane & 7) ^ srow;        // global chunk landing in LDS slot lane&7
  int cx = l16 & 7;                   // frag-read swizzle key (row&7)

  f32x4 acc[4][4];
#pragma unroll
  for (int i = 0; i < 4; i++)
#pragma unroll
    for (int j = 0; j < 4; j++) acc[i][j] = (f32x4){0.f, 0.f, 0.f, 0.f};

  for (int kt = 0; kt < K; kt += BKK) {
    __syncthreads();
#pragma unroll
    for (int i = 0; i < 4; i++) {
      int r0 = wave * 32 + i * 8;
      gll16(A + (mbase + r0 + srow) * (long)K + kt + sck * 8, &As[r0][0]);
      gll16(Bt + (nbase + r0 + srow) * (long)K + kt + sck * 8, &Bs[r0][0]);
    }
    __syncthreads();
#pragma unroll
    for (int ks = 0; ks < BKK; ks += 32) {
      short8 af[4], bfr[4];
      int ch = ((ks >> 3) + quad) ^ cx;   // swizzled chunk for this quad
#pragma unroll
      for (int mt = 0; mt < 4; mt++)
        af[mt] = *(const short8*)&As[wm * 64 + mt * 16 + l16][ch * 8];
#pragma unroll
      for (int nt = 0; nt < 4; nt++)
        bfr[nt] = *(const short8*)&Bs[wn * 64 + nt * 16 + l16][ch * 8];
#pragma unroll
      for (int mt = 0; mt < 4; mt++)
#pragma unroll
        for (int nt = 0; nt < 4; nt++)
          acc[mt][nt] = __builtin_amdgcn_mfma_f32_16x16x32_bf16(
              af[mt], bfr[nt], acc[mt][nt], 0, 0, 0);
    }
  }

  // epilogue: bias/act/rowmask into LDS C-tile, then coalesced 16B stores
  __syncthreads();
#pragma unroll
  for (int nt = 0; nt < 4; nt++) {
    int colt = wn * 64 + nt * 16 + l16;
    float bv = bias ? bias[nbase + colt] : 0.0f;
#pragma unroll
    for (int mt = 0; mt < 4; mt++) {
      int rowt0 = wm * 64 + mt * 16 + quad * 4;
#pragma unroll
      for (int r = 0; r < 4; r++) {
        int rowt = rowt0 + r;
        float v = acc[mt][nt][r] + bv;
        if (act == 1) v = v > 0.f ? v + 1.f : __expf(v);
        else if (act == 2) v = v > 0.f ? v : 0.f;
        if (rowmask) v *= rowmask[mbase + rowt];
        Cs[rowt][colt] = f2b(v);
      }
    }
  }
  __syncthreads();
#pragma unroll
  for (int it = 0; it < 8; it++) {
    int idx = tid + it * 256;
    int row = idx >> 4, c = idx & 15;
    uint4 v = *(const uint4*)&Cs[row][c * 8];
    *(uint4*)(C + (mbase + row) * (long)Nout + nbase + c * 8) = v;
  }
}

// ---------------------------------------------------------------------------
// KV reduce: KV[bh][d][m] += sum_s K[b,s,h,d]*V[b,s,h,m]; Ksum[bh][d] += K.
// Grid (B, H, 10), 256 threads, 32-row stages (15 barrier pairs).
// ---------------------------------------------------------------------------
__global__ __launch_bounds__(256) void kv_reduce(
    const __hip_bfloat16* __restrict__ Kp, const __hip_bfloat16* __restrict__ Vp,
    float* __restrict__ KV, float* __restrict__ Ksum) {
  int b = blockIdx.x, h = blockIdx.y, c = blockIdx.z;
  __shared__ float Kl[32][40], Vl[32][40];   // stride 40: 16B-aligned, 2-way free
  int t = threadIdx.x;
  int lrow = t >> 3, le = (t & 7) * 4;       // staging: 32 rows x 32 elems, 4/thread
  int d = t >> 3, mg = t & 7;                // compute mapping
  float a0 = 0.f, a1 = 0.f, a2 = 0.f, a3 = 0.f, ks = 0.f;
  int base = c * 480;
  for (int st = 0; st < 15; st++) {
    int s0 = base + st * 32;
    __syncthreads();
    {
      long n = (long)b * LSEQ + s0 + lrow;
      ushort4 ku = *(const ushort4*)(Kp + n * 256 + h * 32 + le);
      ushort4 vu = *(const ushort4*)(Vp + n * 256 + h * 32 + le);
      float4 kf = {b2f(ku.x), b2f(ku.y), b2f(ku.z), b2f(ku.w)};
      float4 vf = {b2f(vu.x), b2f(vu.y), b2f(vu.z), b2f(vu.w)};
      *(float4*)&Kl[lrow][le] = kf;
      *(float4*)&Vl[lrow][le] = vf;
    }
    __syncthreads();
#pragma unroll
    for (int ss = 0; ss < 32; ss++) {
      float kd = Kl[ss][d];
      float4 v4 = *(const float4*)&Vl[ss][mg * 4];
      a0 += kd * v4.x; a1 += kd * v4.y; a2 += kd * v4.z; a3 += kd * v4.w;
      if (mg == 0) ks += kd;
    }
  }
  int bh = b * 8 + h;
  float* p = KV + ((long)bh * 32 + d) * 32 + mg * 4;
  atomicAdd(&p[0], a0); atomicAdd(&p[1], a1);
  atomicAdd(&p[2], a2); atomicAdd(&p[3], a3);
  if (mg == 0) atomicAdd(&Ksum[bh * 32 + d], ks);
}

// ---------------------------------------------------------------------------
// Attention output, barrier-free main loop, pure-register q broadcast (shfl).
// Grid (25, B, H); 4 waves; wave handles 8 rows/pass, lane = (rowsub, 4 cols).
// O[n, h*32+m] = (sum_d Q[d]*KV[h][d][m]) / (Q . Ksum[h] + eps)
// ---------------------------------------------------------------------------
__global__ __launch_bounds__(256) void attn_out(
    const __hip_bfloat16* __restrict__ Qp, const float* __restrict__ KV,
    const float* __restrict__ Ksum, __hip_bfloat16* __restrict__ O) {
  int b = blockIdx.y, h = blockIdx.z;
  int bh = b * 8 + h;
  __shared__ float KVl[32][36];        // [d][m], stride 36: 16B-aligned
  int t = threadIdx.x;
  for (int i = t; i < 1024; i += 256) KVl[i >> 5][i & 31] = KV[((long)bh << 10) + i];
  int lane = t & 63, wave = t >> 6;
  int cg = lane & 7, rs = lane >> 3;
  float4 ksr = *(const float4*)&Ksum[bh * 32 + cg * 4];
  __syncthreads();

  int rowEnd = blockIdx.x * 192 + 192;
  for (int r = blockIdx.x * 192 + wave * 8 + rs; r < rowEnd; r += 32) {
    long n = (long)b * LSEQ + r;
    ushort4 qu = *(const ushort4*)(Qp + n * 256 + h * 32 + cg * 4);
    float q0 = b2f(qu.x), q1 = b2f(qu.y), q2 = b2f(qu.z), q3 = b2f(qu.w);
    // denominator: partial dot with Ksum, reduce over the 8-lane row group
    float den = q0 * ksr.x + q1 * ksr.y + q2 * ksr.z + q3 * ksr.w;
    den += __shfl_xor(den, 1);
    den += __shfl_xor(den, 2);
    den += __shfl_xor(den, 4);
    // numerator: broadcast each group's q chunk via shfl (no LDS, no barrier)
    float s0 = 0.f, s1 = 0.f, s2 = 0.f, s3 = 0.f;
    int gbase = lane & ~7;             // first lane of this row group
#pragma unroll
    for (int j = 0; j < 8; j++) {
      int src = gbase | j;             // lane holding q[d=4j..4j+3]
      float qa = __shfl(q0, src);
      float qb = __shfl(q1, src);
      float qc = __shfl(q2, src);
      float qd = __shfl(q3, src);
      float4 k0 = *(const float4*)&KVl[j * 4 + 0][cg * 4];
      float4 k1 = *(const float4*)&KVl[j * 4 + 1][cg * 4];
      float4 k2 = *(const float4*)&KVl[j * 4 + 2][cg * 4];
      float4 k3 = *(const float4*)&KVl[j * 4 + 3][cg * 4];
      s0 += qa * k0.x + qb * k1.x + qc * k2.x + qd * k3.x;
      s1 += qa * k0.y + qb * k1.y + qc * k2.y + qd * k3.y;
      s2 += qa * k0.z + qb * k1.z + qc * k2.z + qd * k3.z;
      s3 += qa * k0.w + qb * k1.w + qc * k2.w + qd * k3.w;
    }
    float inv = 1.0f / (den + 1e-6f);
    ushort4 ou = {f2b(s0 * inv), f2b(s1 * inv), f2b(s2 * inv), f2b(s3 * inv)};
    *(ushort4*)(O + n * 256 + h * 32 + cg * 4) = ou;
  }
}

// ---------------------------------------------------------------------------
// LayerNorm in-place on bf16 rows of 256. 4 rows/block (wave per row).
// ---------------------------------------------------------------------------
__global__ __launch_bounds__(256) void ln_kernel(
    __hip_bfloat16* __restrict__ X, const float* __restrict__ g,
    const float* __restrict__ bt) {
  int wave = threadIdx.x >> 6, lane = threadIdx.x & 63;
  long row = (long)blockIdx.x * 4 + wave;
  __hip_bfloat16* p = X + row * 256 + lane * 4;
  ushort4 u = *(const ushort4*)p;
  float v[4] = {b2f(u.x), b2f(u.y), b2f(u.z), b2f(u.w)};
  float s = v[0] + v[1] + v[2] + v[3];
  float s2 = v[0] * v[0] + v[1] * v[1] + v[2] * v[2] + v[3] * v[3];
#pragma unroll
  for (int off = 32; off; off >>= 1) {
    s += __shfl_xor(s, off);
    s2 += __shfl_xor(s2, off);
  }
  float mu = s * (1.f / 256.f);
  float var = s2 * (1.f / 256.f) - mu * mu;
  float rs = rsqrtf(var + 1e-5f);
  ushort4 o;
  o.x = f2b((v[0] - mu) * rs * g[lane * 4 + 0] + bt[lane * 4 + 0]);
  o.y = f2b((v[1] - mu) * rs * g[lane * 4 + 1] + bt[lane * 4 + 1]);
  o.z = f2b((v[2] - mu) * rs * g[lane * 4 + 2] + bt[lane * 4 + 2]);
  o.w = f2b((v[3] - mu) * rs * g[lane * 4 + 3] + bt[lane * 4 + 3]);
  *(ushort4*)p = o;
}

// ---------------------------------------------------------------------------
// Final: LN(M2) + residual; writes fp32 residual stream and bf16 mirror.
// ---------------------------------------------------------------------------
__global__ __launch_bounds__(256) void final_kernel(
    const __hip_bfloat16* __restrict__ M2, const float* __restrict__ g,
    const float* __restrict__ bt, float* __restrict__ outF,
    __hip_bfloat16* __restrict__ Xb) {
  int wave = threadIdx.x >> 6, lane = threadIdx.x & 63;
  long row = (long)blockIdx.x * 4 + wave;
  const __hip_bfloat16* p = M2 + row * 256 + lane * 4;
  ushort4 u = *(const ushort4*)p;
  float v[4] = {b2f(u.x), b2f(u.y), b2f(u.z), b2f(u.w)};
  float s = v[0] + v[1] + v[2] + v[3];
  float s2 = v[0] * v[0] + v[1] * v[1] + v[2] * v[2] + v[3] * v[3];
#pragma unroll
  for (int off = 32; off; off >>= 1) {
    s += __shfl_xor(s, off);
    s2 += __shfl_xor(s2, off);
  }
  float mu = s * (1.f / 256.f);
  float var = s2 * (1.f / 256.f) - mu * mu;
  float rs = rsqrtf(var + 1e-5f);
  float* op = outF + row * 256 + lane * 4;
  float4 rv = *(float4*)op;
  float r0 = rv.x + ((v[0] - mu) * rs * g[lane * 4 + 0] + bt[lane * 4 + 0]);
  float r1 = rv.y + ((v[1] - mu) * rs * g[lane * 4 + 1] + bt[lane * 4 + 1]);
  float r2 = rv.z + ((v[2] - mu) * rs * g[lane * 4 + 2] + bt[lane * 4 + 2]);
  float r3 = rv.w + ((v[3] - mu) * rs * g[lane * 4 + 3] + bt[lane * 4 + 3]);
  *(float4*)op = (float4){r0, r1, r2, r3};
  ushort4 xb = {f2b(r0), f2b(r1), f2b(r2), f2b(r3)};
  *(ushort4*)(Xb + row * 256 + lane * 4) = xb;
}

// ---------------------------------------------------------------------------
extern "C" void kernel_launch(void* const* d_in, const int* in_sizes, int n_in,
                              void* d_out, int out_size, void* d_ws, size_t ws_size,
                              hipStream_t stream) {
  const float* desc0 = (const float*)d_in[0];
  const float* desc1 = (const float*)d_in[1];
  const float* mask0 = (const float*)d_in[2];
  const float* mask1 = (const float*)d_in[3];
  const float* Wq = (const float*)d_in[4];
  const float* bq = (const float*)d_in[5];
  const float* Wk = (const float*)d_in[6];
  const float* bk = (const float*)d_in[7];
  const float* Wv = (const float*)d_in[8];
  const float* bv = (const float*)d_in[9];
  const float* Wm = (const float*)d_in[10];
  const float* bm = (const float*)d_in[11];
  const float* w1 = (const float*)d_in[12];
  const float* w2 = (const float*)d_in[13];
  const float* g1 = (const float*)d_in[14];
  const float* b1 = (const float*)d_in[15];
  const float* g2 = (const float*)d_in[16];
  const float* b2 = (const float*)d_in[17];

  char* ws = (char*)d_ws;
  auto alloc = [&](size_t bytes) {
    char* p = ws;
    ws += (bytes + 255) & ~(size_t)255;
    return p;
  };
  __hip_bfloat16* WqT = (__hip_bfloat16*)alloc(256 * 256 * 2);
  __hip_bfloat16* WkT = (__hip_bfloat16*)alloc(256 * 256 * 2);
  __hip_bfloat16* WvT = (__hip_bfloat16*)alloc(256 * 256 * 2);
  __hip_bfloat16* WmT = (__hip_bfloat16*)alloc(256 * 256 * 2);
  __hip_bfloat16* w1T = (__hip_bfloat16*)alloc((size_t)8 * 512 * 256 * 2);
  __hip_bfloat16* w2T = (__hip_bfloat16*)alloc((size_t)8 * 256 * 512 * 2);
  __hip_bfloat16* X0b = (__hip_bfloat16*)alloc((size_t)NROWS * 256 * 2);
  __hip_bfloat16* X1b = (__hip_bfloat16*)alloc((size_t)NROWS * 256 * 2);
  __hip_bfloat16* Qb = (__hip_bfloat16*)alloc((size_t)NROWS * 256 * 2);
  __hip_bfloat16* Kb = (__hip_bfloat16*)alloc((size_t)NROWS * 256 * 2);
  __hip_bfloat16* Vb = (__hip_bfloat16*)alloc((size_t)NROWS * 256 * 2);
  __hip_bfloat16* Ab = (__hip_bfloat16*)alloc((size_t)NROWS * 256 * 2);
  __hip_bfloat16* H1b = (__hip_bfloat16*)alloc((size_t)NROWS * 512 * 2);
  float* KVws = (float*)alloc((64 * 1024 + 64 * 32) * 4);
  float* Ksum = KVws + 64 * 1024;

  // weight prep (batched)
  transpose_bf16<<<dim3(8, 8, 1), 256, 0, stream>>>(Wq, WqT, 256, 256);
  transpose_bf16<<<dim3(8, 8, 1), 256, 0, stream>>>(Wk, WkT, 256, 256);
  transpose_bf16<<<dim3(8, 8, 1), 256, 0, stream>>>(Wv, WvT, 256, 256);
  transpose_bf16<<<dim3(8, 8, 1), 256, 0, stream>>>(Wm, WmT, 256, 256);
  transpose_bf16<<<dim3(16, 8, 8), 256, 0, stream>>>(w1, w1T, 256, 512);
  transpose_bf16<<<dim3(8, 16, 8), 256, 0, stream>>>(w2, w2T, 512, 256);

  long nElem = (long)NROWS * 256;
  init_x<<<(nElem + 255) / 256, 256, 0, stream>>>(desc0, desc1, (float*)d_out,
                                                  X0b, X1b, nElem);

  auto gemm = [&](const __hip_bfloat16* A, const __hip_bfloat16* Bt,
                  const float* bias, const float* rm, __hip_bfloat16* C,
                  int Nout, int K, int act) {
    dim3 grid(Nout / BN, NROWS / BM);
    gemm_bt<<<grid, 256, 0, stream>>>(A, Bt, bias, rm, C, NROWS, Nout, K, act);
  };

  auto layer = [&](int x, int s, int i) {
    __hip_bfloat16* Xx = x ? X1b : X0b;
    __hip_bfloat16* Xs = s ? X1b : X0b;
    const float* mx = x ? mask1 : mask0;
    const float* ms = s ? mask1 : mask0;
    gemm(Xx, WqT, bq, mx, Qb, 256, 256, 1);            // Q = elu+1, *qmask
    gemm(Xs, WkT, bk, ms, Kb, 256, 256, 1);            // K = elu+1, *kmask
    gemm(Xs, WvT, bv, ms, Vb, 256, 256, 0);            // V = *kmask
    hipMemsetAsync(KVws, 0, (64 * 1024 + 64 * 32) * 4, stream);
    kv_reduce<<<dim3(BATCH, NHEAD, 10), 256, 0, stream>>>(Kb, Vb, KVws, Ksum);
    attn_out<<<dim3(25, BATCH, NHEAD), 256, 0, stream>>>(Qb, KVws, Ksum, Ab);
    gemm(Ab, WmT, bm, nullptr, Kb, 256, 256, 0);       // msg (into Kb)
    ln_kernel<<<NROWS / 4, 256, 0, stream>>>(Kb, g1 + i * 256, b1 + i * 256);
    gemm(Kb, w1T + (size_t)i * 512 * 256, nullptr, nullptr, H1b, 512, 256, 2);
    gemm(H1b, w2T + (size_t)i * 256 * 512, nullptr, nullptr, Vb, 256, 512, 0);
    final_kernel<<<NROWS / 4, 256, 0, stream>>>(
        Vb, g2 + i * 256, b2 + i * 256, (float*)d_out + (size_t)x * nElem, Xx);
  };

  for (int i = 0; i < 8; i++) {
    if (i % 2 == 0) {        // self
      layer(0, 0, i);
      layer(1, 1, i);
    } else {                 // cross (desc1 sees UPDATED desc0)
      layer(0, 1, i);
      layer(1, 0, i);
    }
  }
}

// Round 7
// 3394.630 us; speedup vs baseline: 1.3732x; 1.0456x over previous
//
#include <hip/hip_runtime.h>
#include <hip/hip_bf16.h>

typedef __attribute__((ext_vector_type(8))) short short8;
typedef __attribute__((ext_vector_type(4))) float f32x4;

#define NROWS 38400      // B*L = 8*4800
#define LSEQ 4800
#define BATCH 8
#define NHEAD 8
#define QKV_LD 768

__device__ inline float b2f(ushort u) {
  union { ushort s; __hip_bfloat16 h; } c;
  c.s = u;
  return __bfloat162float(c.h);
}
__device__ inline ushort f2b(float f) {
  union { ushort s; __hip_bfloat16 h; } c;
  c.h = __float2bfloat16(f);
  return c.s;
}

// async global->LDS, 16B per lane. LDS dst = wave-uniform base + lane*16.
__device__ inline void gll16(const void* g, void* l) {
  __builtin_amdgcn_global_load_lds(
      (const __attribute__((address_space(1))) void*)g,
      (__attribute__((address_space(3))) void*)l, 16, 0, 0);
}

// ---------------------------------------------------------------------------
// Tiled transpose + fp32->bf16: dst[c][r] = src[r][c], batched over blockIdx.z.
// ---------------------------------------------------------------------------
__global__ __launch_bounds__(256) void transpose_bf16(
    const float* __restrict__ src, __hip_bfloat16* __restrict__ dst, int R, int C) {
  src += (size_t)blockIdx.z * R * C;
  dst += (size_t)blockIdx.z * R * C;
  __shared__ float tile[32][33];
  int bx = blockIdx.x, by = blockIdx.y;
  int tx = threadIdx.x & 31, ty = threadIdx.x >> 5;
  for (int rr = ty; rr < 32; rr += 8)
    tile[rr][tx] = src[(long)(by * 32 + rr) * C + bx * 32 + tx];
  __syncthreads();
  for (int rr = ty; rr < 32; rr += 8)
    dst[(long)(bx * 32 + rr) * R + by * 32 + tx] = __float2bfloat16(tile[tx][rr]);
}

// ---------------------------------------------------------------------------
// Init (float4-vectorized): residual stream + bf16 mirrors.
// ---------------------------------------------------------------------------
__global__ __launch_bounds__(256) void init_x(
    const float* __restrict__ d0, const float* __restrict__ d1,
    float* __restrict__ outF, __hip_bfloat16* __restrict__ X0b,
    __hip_bfloat16* __restrict__ X1b, long n4) {
  long i = (long)blockIdx.x * 256 + threadIdx.x;
  if (i < n4) {
    float4 a = ((const float4*)d0)[i];
    float4 b = ((const float4*)d1)[i];
    ((float4*)outF)[i] = a;
    ((float4*)outF)[n4 + i] = b;
    ushort4 ua = {f2b(a.x), f2b(a.y), f2b(a.z), f2b(a.w)};
    ushort4 ub = {f2b(b.x), f2b(b.y), f2b(b.z), f2b(b.w)};
    ((ushort4*)X0b)[i] = ua;
    ((ushort4*)X1b)[i] = ub;
  }
}

// ---------------------------------------------------------------------------
// Fused QKV projection GEMM. BM=128, BN=128, K=256, ldA=256, ldC=768.
// Global col g = col0 + blockIdx.x*128 + colt; seg = g>>8 picks:
//   seg 0: bias bq, elu+1, rowmask mq;  seg 1: bk, elu+1, mkv;  seg 2: bv, mkv.
// ---------------------------------------------------------------------------
__global__ __launch_bounds__(256) void gemm_qkv(
    const __hip_bfloat16* __restrict__ A, const __hip_bfloat16* __restrict__ Bt,
    __hip_bfloat16* __restrict__ C, int col0,
    const float* __restrict__ bq, const float* __restrict__ bk,
    const float* __restrict__ bv, const float* __restrict__ mq,
    const float* __restrict__ mkv) {
  __shared__ alignas(16) char smem[128 * 136 * 2];
  __hip_bfloat16 (*As)[64] = (__hip_bfloat16(*)[64])smem;
  __hip_bfloat16 (*Bs)[64] = (__hip_bfloat16(*)[64])(smem + 128 * 64 * 2);
  ushort (*Cs)[136] = (ushort(*)[136])smem;

  int tid = threadIdx.x;
  int wave = tid >> 6, lane = tid & 63;
  int wm = wave & 1, wn = wave >> 1;
  int quad = lane >> 4, l16 = lane & 15;
  long mbase = (long)blockIdx.y * 128;
  int nbase = blockIdx.x * 128;

  int srow = lane >> 3;
  int sck = (lane & 7) ^ srow;
  int cx = l16 & 7;

  f32x4 acc[4][4];
#pragma unroll
  for (int i = 0; i < 4; i++)
#pragma unroll
    for (int j = 0; j < 4; j++) acc[i][j] = (f32x4){0.f, 0.f, 0.f, 0.f};

  for (int kt = 0; kt < 256; kt += 64) {
    __syncthreads();
#pragma unroll
    for (int i = 0; i < 4; i++) {
      int r0 = wave * 32 + i * 8;
      gll16(A + (mbase + r0 + srow) * 256 + kt + sck * 8, &As[r0][0]);
      gll16(Bt + (long)(nbase + r0 + srow) * 256 + kt + sck * 8, &Bs[r0][0]);
    }
    __syncthreads();
#pragma unroll
    for (int ks = 0; ks < 64; ks += 32) {
      short8 af[4], bfr[4];
      int ch = ((ks >> 3) + quad) ^ cx;
#pragma unroll
      for (int mt = 0; mt < 4; mt++)
        af[mt] = *(const short8*)&As[wm * 64 + mt * 16 + l16][ch * 8];
#pragma unroll
      for (int nt = 0; nt < 4; nt++)
        bfr[nt] = *(const short8*)&Bs[wn * 64 + nt * 16 + l16][ch * 8];
#pragma unroll
      for (int mt = 0; mt < 4; mt++)
#pragma unroll
        for (int nt = 0; nt < 4; nt++)
          acc[mt][nt] = __builtin_amdgcn_mfma_f32_16x16x32_bf16(
              af[mt], bfr[nt], acc[mt][nt], 0, 0, 0);
    }
  }

  __syncthreads();
  int gc0 = col0 + nbase;
#pragma unroll
  for (int nt = 0; nt < 4; nt++) {
    int colt = wn * 64 + nt * 16 + l16;
    int gcol = gc0 + colt;
    int seg = gcol >> 8;
    int ci = gcol & 255;
    float bvv = (seg == 0) ? bq[ci] : (seg == 1) ? bk[ci] : bv[ci];
    const float* mask = (seg == 0) ? mq : mkv;
    bool doelu = seg < 2;
#pragma unroll
    for (int mt = 0; mt < 4; mt++) {
      int rowt0 = wm * 64 + mt * 16 + quad * 4;
#pragma unroll
      for (int r = 0; r < 4; r++) {
        int rowt = rowt0 + r;
        float v = acc[mt][nt][r] + bvv;
        if (doelu) v = v > 0.f ? v + 1.f : __expf(v);
        v *= mask[mbase + rowt];
        Cs[rowt][colt] = f2b(v);
      }
    }
  }
  __syncthreads();
#pragma unroll
  for (int it = 0; it < 8; it++) {
    int idx = tid + it * 256;
    int row = idx >> 4, c = idx & 15;
    uint4 v = *(const uint4*)&Cs[row][c * 8];
    *(uint4*)(C + (mbase + row) * (long)QKV_LD + gc0 + c * 8) = v;
  }
}

// ---------------------------------------------------------------------------
// w1 GEMM: H1[m][n] = relu(sum_k M[m][k]*w1T[n][k]). BM=BN=128, K=256, ldC=512.
// ---------------------------------------------------------------------------
__global__ __launch_bounds__(256) void gemm_w1(
    const __hip_bfloat16* __restrict__ A, const __hip_bfloat16* __restrict__ Bt,
    __hip_bfloat16* __restrict__ C) {
  __shared__ alignas(16) char smem[128 * 136 * 2];
  __hip_bfloat16 (*As)[64] = (__hip_bfloat16(*)[64])smem;
  __hip_bfloat16 (*Bs)[64] = (__hip_bfloat16(*)[64])(smem + 128 * 64 * 2);
  ushort (*Cs)[136] = (ushort(*)[136])smem;

  int tid = threadIdx.x;
  int wave = tid >> 6, lane = tid & 63;
  int wm = wave & 1, wn = wave >> 1;
  int quad = lane >> 4, l16 = lane & 15;
  long mbase = (long)blockIdx.y * 128;
  int nbase = blockIdx.x * 128;

  int srow = lane >> 3;
  int sck = (lane & 7) ^ srow;
  int cx = l16 & 7;

  f32x4 acc[4][4];
#pragma unroll
  for (int i = 0; i < 4; i++)
#pragma unroll
    for (int j = 0; j < 4; j++) acc[i][j] = (f32x4){0.f, 0.f, 0.f, 0.f};

  for (int kt = 0; kt < 256; kt += 64) {
    __syncthreads();
#pragma unroll
    for (int i = 0; i < 4; i++) {
      int r0 = wave * 32 + i * 8;
      gll16(A + (mbase + r0 + srow) * 256 + kt + sck * 8, &As[r0][0]);
      gll16(Bt + (long)(nbase + r0 + srow) * 256 + kt + sck * 8, &Bs[r0][0]);
    }
    __syncthreads();
#pragma unroll
    for (int ks = 0; ks < 64; ks += 32) {
      short8 af[4], bfr[4];
      int ch = ((ks >> 3) + quad) ^ cx;
#pragma unroll
      for (int mt = 0; mt < 4; mt++)
        af[mt] = *(const short8*)&As[wm * 64 + mt * 16 + l16][ch * 8];
#pragma unroll
      for (int nt = 0; nt < 4; nt++)
        bfr[nt] = *(const short8*)&Bs[wn * 64 + nt * 16 + l16][ch * 8];
#pragma unroll
      for (int mt = 0; mt < 4; mt++)
#pragma unroll
        for (int nt = 0; nt < 4; nt++)
          acc[mt][nt] = __builtin_amdgcn_mfma_f32_16x16x32_bf16(
              af[mt], bfr[nt], acc[mt][nt], 0, 0, 0);
    }
  }

  __syncthreads();
#pragma unroll
  for (int nt = 0; nt < 4; nt++) {
    int colt = wn * 64 + nt * 16 + l16;
#pragma unroll
    for (int mt = 0; mt < 4; mt++) {
      int rowt0 = wm * 64 + mt * 16 + quad * 4;
#pragma unroll
      for (int r = 0; r < 4; r++) {
        float v = acc[mt][nt][r];
        Cs[rowt0 + r][colt] = f2b(v > 0.f ? v : 0.f);
      }
    }
  }
  __syncthreads();
#pragma unroll
  for (int it = 0; it < 8; it++) {
    int idx = tid + it * 256;
    int row = idx >> 4, c = idx & 15;
    uint4 v = *(const uint4*)&Cs[row][c * 8];
    *(uint4*)(C + (mbase + row) * 512L + nbase + c * 8) = v;
  }
}

// ---------------------------------------------------------------------------
// Wm GEMM + bias + LayerNorm fused. BM=64, BN=256 (full row), K=256.
// Grid (NROWS/64). 4 waves, wave w covers cols w*64..w*64+63, all 64 rows.
// ---------------------------------------------------------------------------
__global__ __launch_bounds__(256) void gemm_ln(
    const __hip_bfloat16* __restrict__ A, const __hip_bfloat16* __restrict__ Bt,
    const float* __restrict__ bias, const float* __restrict__ g,
    const float* __restrict__ bln, __hip_bfloat16* __restrict__ C) {
  __shared__ alignas(16) char smem[8192 + 32768];   // As 64x64 + Bs 256x64
  __hip_bfloat16 (*As)[64] = (__hip_bfloat16(*)[64])smem;
  __hip_bfloat16 (*Bs)[64] = (__hip_bfloat16(*)[64])(smem + 8192);
  ushort (*Cs)[264] = (ushort(*)[264])smem;         // 64x264 = 33792 B (union ok)
  __shared__ float pS[4][64], pS2[4][64], muA[64], rsA[64];

  int tid = threadIdx.x;
  int wave = tid >> 6, lane = tid & 63;
  int wn = wave;
  int quad = lane >> 4, l16 = lane & 15;
  long mbase = (long)blockIdx.x * 64;

  int srow = lane >> 3;
  int sck = (lane & 7) ^ srow;
  int cx = l16 & 7;

  f32x4 acc[4][4];
#pragma unroll
  for (int i = 0; i < 4; i++)
#pragma unroll
    for (int j = 0; j < 4; j++) acc[i][j] = (f32x4){0.f, 0.f, 0.f, 0.f};

  for (int kt = 0; kt < 256; kt += 64) {
    __syncthreads();
#pragma unroll
    for (int j = 0; j < 2; j++) {
      int r0 = wave * 16 + j * 8;
      gll16(A + (mbase + r0 + srow) * 256 + kt + sck * 8, &As[r0][0]);
    }
#pragma unroll
    for (int j = 0; j < 8; j++) {
      int r0 = wave * 64 + j * 8;
      gll16(Bt + (r0 + srow) * 256 + kt + sck * 8, &Bs[r0][0]);
    }
    __syncthreads();
#pragma unroll
    for (int ks = 0; ks < 64; ks += 32) {
      short8 af[4], bfr[4];
      int ch = ((ks >> 3) + quad) ^ cx;
#pragma unroll
      for (int mt = 0; mt < 4; mt++)
        af[mt] = *(const short8*)&As[mt * 16 + l16][ch * 8];
#pragma unroll
      for (int nt = 0; nt < 4; nt++)
        bfr[nt] = *(const short8*)&Bs[wn * 64 + nt * 16 + l16][ch * 8];
#pragma unroll
      for (int mt = 0; mt < 4; mt++)
#pragma unroll
        for (int nt = 0; nt < 4; nt++)
          acc[mt][nt] = __builtin_amdgcn_mfma_f32_16x16x32_bf16(
              af[mt], bfr[nt], acc[mt][nt], 0, 0, 0);
    }
  }

  // per-lane params for its 4 columns
  float br[4], gr[4], blr[4];
#pragma unroll
  for (int nt = 0; nt < 4; nt++) {
    int gcol = wn * 64 + nt * 16 + l16;
    br[nt] = bias[gcol];
    gr[nt] = g[gcol];
    blr[nt] = bln[gcol];
  }
  // row partial sums over this wave's 64 cols
#pragma unroll
  for (int mt = 0; mt < 4; mt++)
#pragma unroll
    for (int r = 0; r < 4; r++) {
      float s = 0.f, s2 = 0.f;
#pragma unroll
      for (int nt = 0; nt < 4; nt++) {
        float v = acc[mt][nt][r] + br[nt];
        s += v;
        s2 += v * v;
      }
      s += __shfl_xor(s, 1);  s2 += __shfl_xor(s2, 1);
      s += __shfl_xor(s, 2);  s2 += __shfl_xor(s2, 2);
      s += __shfl_xor(s, 4);  s2 += __shfl_xor(s2, 4);
      s += __shfl_xor(s, 8);  s2 += __shfl_xor(s2, 8);
      if (l16 == 0) {
        int row = mt * 16 + quad * 4 + r;
        pS[wn][row] = s;
        pS2[wn][row] = s2;
      }
    }
  __syncthreads();
  if (tid < 64) {
    float S = pS[0][tid] + pS[1][tid] + pS[2][tid] + pS[3][tid];
    float S2 = pS2[0][tid] + pS2[1][tid] + pS2[2][tid] + pS2[3][tid];
    float mu = S * (1.f / 256.f);
    float var = S2 * (1.f / 256.f) - mu * mu;
    muA[tid] = mu;
    rsA[tid] = rsqrtf(var + 1e-5f);
  }
  __syncthreads();
#pragma unroll
  for (int mt = 0; mt < 4; mt++)
#pragma unroll
    for (int r = 0; r < 4; r++) {
      int row = mt * 16 + quad * 4 + r;
      float mu = muA[row], rs = rsA[row];
#pragma unroll
      for (int nt = 0; nt < 4; nt++) {
        float v = acc[mt][nt][r] + br[nt];
        Cs[row][wn * 64 + nt * 16 + l16] = f2b((v - mu) * rs * gr[nt] + blr[nt]);
      }
    }
  __syncthreads();
#pragma unroll
  for (int it = 0; it < 8; it++) {
    int idx = tid + it * 256;   // 0..2047 -> 64 rows x 32 chunks
    int row = idx >> 5, c = idx & 31;
    uint4 v = *(const uint4*)&Cs[row][c * 8];
    *(uint4*)(C + (mbase + row) * 256L + c * 8) = v;
  }
}

// ---------------------------------------------------------------------------
// w2 GEMM + LayerNorm + residual fused. BM=64, BN=256, K=512.
// outF (fp32 residual stream) updated in-place; Xb = bf16 mirror.
// ---------------------------------------------------------------------------
__global__ __launch_bounds__(256) void gemm_final(
    const __hip_bfloat16* __restrict__ A, const __hip_bfloat16* __restrict__ Bt,
    const float* __restrict__ g, const float* __restrict__ bln,
    float* __restrict__ outF, __hip_bfloat16* __restrict__ Xb) {
  __shared__ alignas(16) char smem[8192 + 32768];
  __hip_bfloat16 (*As)[64] = (__hip_bfloat16(*)[64])smem;
  __hip_bfloat16 (*Bs)[64] = (__hip_bfloat16(*)[64])(smem + 8192);
  ushort (*Cs)[264] = (ushort(*)[264])smem;
  __shared__ float pS[4][64], pS2[4][64], muA[64], rsA[64];

  int tid = threadIdx.x;
  int wave = tid >> 6, lane = tid & 63;
  int wn = wave;
  int quad = lane >> 4, l16 = lane & 15;
  long mbase = (long)blockIdx.x * 64;

  int srow = lane >> 3;
  int sck = (lane & 7) ^ srow;
  int cx = l16 & 7;

  f32x4 acc[4][4];
#pragma unroll
  for (int i = 0; i < 4; i++)
#pragma unroll
    for (int j = 0; j < 4; j++) acc[i][j] = (f32x4){0.f, 0.f, 0.f, 0.f};

  for (int kt = 0; kt < 512; kt += 64) {
    __syncthreads();
#pragma unroll
    for (int j = 0; j < 2; j++) {
      int r0 = wave * 16 + j * 8;
      gll16(A + (mbase + r0 + srow) * 512 + kt + sck * 8, &As[r0][0]);
    }
#pragma unroll
    for (int j = 0; j < 8; j++) {
      int r0 = wave * 64 + j * 8;
      gll16(Bt + (r0 + srow) * 512L + kt + sck * 8, &Bs[r0][0]);
    }
    __syncthreads();
#pragma unroll
    for (int ks = 0; ks < 64; ks += 32) {
      short8 af[4], bfr[4];
      int ch = ((ks >> 3) + quad) ^ cx;
#pragma unroll
      for (int mt = 0; mt < 4; mt++)
        af[mt] = *(const short8*)&As[mt * 16 + l16][ch * 8];
#pragma unroll
      for (int nt = 0; nt < 4; nt++)
        bfr[nt] = *(const short8*)&Bs[wn * 64 + nt * 16 + l16][ch * 8];
#pragma unroll
      for (int mt = 0; mt < 4; mt++)
#pragma unroll
        for (int nt = 0; nt < 4; nt++)
          acc[mt][nt] = __builtin_amdgcn_mfma_f32_16x16x32_bf16(
              af[mt], bfr[nt], acc[mt][nt], 0, 0, 0);
    }
  }

  float gr[4], blr[4];
#pragma unroll
  for (int nt = 0; nt < 4; nt++) {
    int gcol = wn * 64 + nt * 16 + l16;
    gr[nt] = g[gcol];
    blr[nt] = bln[gcol];
  }
#pragma unroll
  for (int mt = 0; mt < 4; mt++)
#pragma unroll
    for (int r = 0; r < 4; r++) {
      float s = 0.f, s2 = 0.f;
#pragma unroll
      for (int nt = 0; nt < 4; nt++) {
        float v = acc[mt][nt][r];
        s += v;
        s2 += v * v;
      }
      s += __shfl_xor(s, 1);  s2 += __shfl_xor(s2, 1);
      s += __shfl_xor(s, 2);  s2 += __shfl_xor(s2, 2);
      s += __shfl_xor(s, 4);  s2 += __shfl_xor(s2, 4);
      s += __shfl_xor(s, 8);  s2 += __shfl_xor(s2, 8);
      if (l16 == 0) {
        int row = mt * 16 + quad * 4 + r;
        pS[wn][row] = s;
        pS2[wn][row] = s2;
      }
    }
  __syncthreads();
  if (tid < 64) {
    float S = pS[0][tid] + pS[1][tid] + pS[2][tid] + pS[3][tid];
    float S2 = pS2[0][tid] + pS2[1][tid] + pS2[2][tid] + pS2[3][tid];
    float mu = S * (1.f / 256.f);
    float var = S2 * (1.f / 256.f) - mu * mu;
    muA[tid] = mu;
    rsA[tid] = rsqrtf(var + 1e-5f);
  }
  __syncthreads();
#pragma unroll
  for (int mt = 0; mt < 4; mt++)
#pragma unroll
    for (int r = 0; r < 4; r++) {
      int row = mt * 16 + quad * 4 + r;
      float mu = muA[row], rs = rsA[row];
#pragma unroll
      for (int nt = 0; nt < 4; nt++) {
        int gcol = wn * 64 + nt * 16 + l16;
        float ln = (acc[mt][nt][r] - mu) * rs * gr[nt] + blr[nt];
        float* op = outF + (mbase + row) * 256 + gcol;
        float rr = *op + ln;          // residual in fp32
        *op = rr;
        Cs[row][gcol] = f2b(rr);
      }
    }
  __syncthreads();
#pragma unroll
  for (int it = 0; it < 8; it++) {
    int idx = tid + it * 256;
    int row = idx >> 5, c = idx & 31;
    uint4 v = *(const uint4*)&Cs[row][c * 8];
    *(uint4*)(Xb + (mbase + row) * 256L + c * 8) = v;
  }
}

// ---------------------------------------------------------------------------
// KV reduce from QKV buffer (stride 768; K at +256, V at +512).
// ---------------------------------------------------------------------------
__global__ __launch_bounds__(256) void kv_reduce(
    const __hip_bfloat16* __restrict__ QKV, float* __restrict__ KV,
    float* __restrict__ Ksum) {
  int b = blockIdx.x, h = blockIdx.y, c = blockIdx.z;
  __shared__ float Kl[32][40], Vl[32][40];
  int t = threadIdx.x;
  int lrow = t >> 3, le = (t & 7) * 4;
  int d = t >> 3, mg = t & 7;
  float a0 = 0.f, a1 = 0.f, a2 = 0.f, a3 = 0.f, ks = 0.f;
  int base = c * 480;
  for (int st = 0; st < 15; st++) {
    int s0 = base + st * 32;
    __syncthreads();
    {
      long n = (long)b * LSEQ + s0 + lrow;
      ushort4 ku = *(const ushort4*)(QKV + n * QKV_LD + 256 + h * 32 + le);
      ushort4 vu = *(const ushort4*)(QKV + n * QKV_LD + 512 + h * 32 + le);
      float4 kf = {b2f(ku.x), b2f(ku.y), b2f(ku.z), b2f(ku.w)};
      float4 vf = {b2f(vu.x), b2f(vu.y), b2f(vu.z), b2f(vu.w)};
      *(float4*)&Kl[lrow][le] = kf;
      *(float4*)&Vl[lrow][le] = vf;
    }
    __syncthreads();
#pragma unroll
    for (int ss = 0; ss < 32; ss++) {
      float kd = Kl[ss][d];
      float4 v4 = *(const float4*)&Vl[ss][mg * 4];
      a0 += kd * v4.x; a1 += kd * v4.y; a2 += kd * v4.z; a3 += kd * v4.w;
      if (mg == 0) ks += kd;
    }
  }
  int bh = b * 8 + h;
  float* p = KV + ((long)bh * 32 + d) * 32 + mg * 4;
  atomicAdd(&p[0], a0); atomicAdd(&p[1], a1);
  atomicAdd(&p[2], a2); atomicAdd(&p[3], a3);
  if (mg == 0) atomicAdd(&Ksum[bh * 32 + d], ks);
}

// ---------------------------------------------------------------------------
// Attention output from QKV buffer (Q stride 768); writes Ab (stride 256).
// ---------------------------------------------------------------------------
__global__ __launch_bounds__(256) void attn_out(
    const __hip_bfloat16* __restrict__ QKV, const float* __restrict__ KV,
    const float* __restrict__ Ksum, __hip_bfloat16* __restrict__ O) {
  int b = blockIdx.y, h = blockIdx.z;
  int bh = b * 8 + h;
  __shared__ float KVl[32][36];
  int t = threadIdx.x;
  for (int i = t; i < 1024; i += 256) KVl[i >> 5][i & 31] = KV[((long)bh << 10) + i];
  int lane = t & 63, wave = t >> 6;
  int cg = lane & 7, rs = lane >> 3;
  float4 ksr = *(const float4*)&Ksum[bh * 32 + cg * 4];
  __syncthreads();

  int rowEnd = blockIdx.x * 192 + 192;
  for (int r = blockIdx.x * 192 + wave * 8 + rs; r < rowEnd; r += 32) {
    long n = (long)b * LSEQ + r;
    ushort4 qu = *(const ushort4*)(QKV + n * QKV_LD + h * 32 + cg * 4);
    float q0 = b2f(qu.x), q1 = b2f(qu.y), q2 = b2f(qu.z), q3 = b2f(qu.w);
    float den = q0 * ksr.x + q1 * ksr.y + q2 * ksr.z + q3 * ksr.w;
    den += __shfl_xor(den, 1);
    den += __shfl_xor(den, 2);
    den += __shfl_xor(den, 4);
    float s0 = 0.f, s1 = 0.f, s2 = 0.f, s3 = 0.f;
    int gbase = lane & ~7;
#pragma unroll
    for (int j = 0; j < 8; j++) {
      int src = gbase | j;
      float qa = __shfl(q0, src);
      float qb = __shfl(q1, src);
      float qc = __shfl(q2, src);
      float qd = __shfl(q3, src);
      float4 k0 = *(const float4*)&KVl[j * 4 + 0][cg * 4];
      float4 k1 = *(const float4*)&KVl[j * 4 + 1][cg * 4];
      float4 k2 = *(const float4*)&KVl[j * 4 + 2][cg * 4];
      float4 k3 = *(const float4*)&KVl[j * 4 + 3][cg * 4];
      s0 += qa * k0.x + qb * k1.x + qc * k2.x + qd * k3.x;
      s1 += qa * k0.y + qb * k1.y + qc * k2.y + qd * k3.y;
      s2 += qa * k0.z + qb * k1.z + qc * k2.z + qd * k3.z;
      s3 += qa * k0.w + qb * k1.w + qc * k2.w + qd * k3.w;
    }
    float inv = 1.0f / (den + 1e-6f);
    ushort4 ou = {f2b(s0 * inv), f2b(s1 * inv), f2b(s2 * inv), f2b(s3 * inv)};
    *(ushort4*)(O + n * 256 + h * 32 + cg * 4) = ou;
  }
}

// ---------------------------------------------------------------------------
extern "C" void kernel_launch(void* const* d_in, const int* in_sizes, int n_in,
                              void* d_out, int out_size, void* d_ws, size_t ws_size,
                              hipStream_t stream) {
  const float* desc0 = (const float*)d_in[0];
  const float* desc1 = (const float*)d_in[1];
  const float* mask0 = (const float*)d_in[2];
  const float* mask1 = (const float*)d_in[3];
  const float* Wq = (const float*)d_in[4];
  const float* bq = (const float*)d_in[5];
  const float* Wk = (const float*)d_in[6];
  const float* bk = (const float*)d_in[7];
  const float* Wv = (const float*)d_in[8];
  const float* bv = (const float*)d_in[9];
  const float* Wm = (const float*)d_in[10];
  const float* bm = (const float*)d_in[11];
  const float* w1 = (const float*)d_in[12];
  const float* w2 = (const float*)d_in[13];
  const float* g1 = (const float*)d_in[14];
  const float* b1 = (const float*)d_in[15];
  const float* g2 = (const float*)d_in[16];
  const float* b2 = (const float*)d_in[17];

  char* ws = (char*)d_ws;
  auto alloc = [&](size_t bytes) {
    char* p = ws;
    ws += (bytes + 255) & ~(size_t)255;
    return p;
  };
  __hip_bfloat16* WqkvT = (__hip_bfloat16*)alloc((size_t)768 * 256 * 2);
  __hip_bfloat16* WmT = (__hip_bfloat16*)alloc(256 * 256 * 2);
  __hip_bfloat16* w1T = (__hip_bfloat16*)alloc((size_t)8 * 512 * 256 * 2);
  __hip_bfloat16* w2T = (__hip_bfloat16*)alloc((size_t)8 * 256 * 512 * 2);
  __hip_bfloat16* X0b = (__hip_bfloat16*)alloc((size_t)NROWS * 256 * 2);
  __hip_bfloat16* X1b = (__hip_bfloat16*)alloc((size_t)NROWS * 256 * 2);
  __hip_bfloat16* QKV = (__hip_bfloat16*)alloc((size_t)NROWS * QKV_LD * 2);
  __hip_bfloat16* Ab = (__hip_bfloat16*)alloc((size_t)NROWS * 256 * 2);
  __hip_bfloat16* Mb = (__hip_bfloat16*)alloc((size_t)NROWS * 256 * 2);
  __hip_bfloat16* H1b = (__hip_bfloat16*)alloc((size_t)NROWS * 512 * 2);
  float* KVws = (float*)alloc((64 * 1024 + 64 * 32) * 4);
  float* Ksum = KVws + 64 * 1024;

  // weight prep
  transpose_bf16<<<dim3(8, 8, 1), 256, 0, stream>>>(Wq, WqkvT, 256, 256);
  transpose_bf16<<<dim3(8, 8, 1), 256, 0, stream>>>(Wk, WqkvT + 65536, 256, 256);
  transpose_bf16<<<dim3(8, 8, 1), 256, 0, stream>>>(Wv, WqkvT + 131072, 256, 256);
  transpose_bf16<<<dim3(8, 8, 1), 256, 0, stream>>>(Wm, WmT, 256, 256);
  transpose_bf16<<<dim3(16, 8, 8), 256, 0, stream>>>(w1, w1T, 256, 512);
  transpose_bf16<<<dim3(8, 16, 8), 256, 0, stream>>>(w2, w2T, 512, 256);

  long nElem = (long)NROWS * 256;
  long n4 = nElem / 4;
  init_x<<<(n4 + 255) / 256, 256, 0, stream>>>(desc0, desc1, (float*)d_out,
                                               X0b, X1b, n4);

  auto layer = [&](int x, int s, int i) {
    __hip_bfloat16* Xx = x ? X1b : X0b;
    __hip_bfloat16* Xs = s ? X1b : X0b;
    const float* mx = x ? mask1 : mask0;
    const float* ms = s ? mask1 : mask0;
    if (x == s) {
      gemm_qkv<<<dim3(6, 300), 256, 0, stream>>>(Xx, WqkvT, QKV, 0,
                                                 bq, bk, bv, mx, ms);
    } else {
      gemm_qkv<<<dim3(2, 300), 256, 0, stream>>>(Xx, WqkvT, QKV, 0,
                                                 bq, bk, bv, mx, ms);
      gemm_qkv<<<dim3(4, 300), 256, 0, stream>>>(Xs, WqkvT + 65536, QKV, 256,
                                                 bq, bk, bv, mx, ms);
    }
    hipMemsetAsync(KVws, 0, (64 * 1024 + 64 * 32) * 4, stream);
    kv_reduce<<<dim3(BATCH, NHEAD, 10), 256, 0, stream>>>(QKV, KVws, Ksum);
    attn_out<<<dim3(25, BATCH, NHEAD), 256, 0, stream>>>(QKV, KVws, Ksum, Ab);
    gemm_ln<<<NROWS / 64, 256, 0, stream>>>(Ab, WmT, bm, g1 + i * 256,
                                            b1 + i * 256, Mb);
    gemm_w1<<<dim3(4, 300), 256, 0, stream>>>(Mb, w1T + (size_t)i * 512 * 256, H1b);
    gemm_final<<<NROWS / 64, 256, 0, stream>>>(
        H1b, w2T + (size_t)i * 256 * 512, g2 + i * 256, b2 + i * 256,
        (float*)d_out + (size_t)x * nElem, Xx);
  };

  for (int i = 0; i < 8; i++) {
    if (i % 2 == 0) {        // self
      layer(0, 0, i);
      layer(1, 1, i);
    } else {                 // cross (desc1 sees UPDATED desc0)
      layer(0, 1, i);
      layer(1, 0, i);
    }
  }
}